// Round 5
// baseline (3476.554 us; speedup 1.0000x reference)
//
#include <hip/hip_runtime.h>
#include <hip/hip_bf16.h>
#include <cstdint>

#define RINGN 256
#define DD    128
#define SDN   42
#define G3N   126
#define INN   64
#define BN    512
#define TN    512
#define NCN   1000
#define HS    44          // padded h row stride (floats)
#define GXS   128         // padded gx row stride (floats) -> 512B rows
#define BT    (BN * TN)   // 262144 rows
#define WPB   8           // waves (batch elements) per rec block

typedef float v2f __attribute__((ext_vector_type(2)));

__device__ __forceinline__ float sigm(float x)    { return 1.0f / (1.0f + __expf(-x)); }
__device__ __forceinline__ float tanhfast(float x){ float e = __expf(2.0f * x); return 1.0f - 2.0f / (e + 1.0f); }
__device__ __forceinline__ float wrap256(float x) { return x - 256.0f * floorf(x * 0.00390625f); }

// normalized taps (for non-critical kernels)
__device__ __forceinline__ void taps_norm(float p, int* pos, float* w) {
  float base = floorf(p);
  float frac = p - base;
  int ib = (int)base;
  float e[5];
  float s = 0.0f;
#pragma unroll
  for (int k = 0; k < 5; k++) {
    float d = (float)(k - 2) - frac;
    e[k] = __expf(-(d * d) * 0.125f);
    s += e[k];
    pos[k] = (ib + k - 2) & 255;
  }
  float inv = 1.0f / s;
#pragma unroll
  for (int k = 0; k < 5; k++) w[k] = e[k] * inv;
}

// DPP full-wave sum, result broadcast via readlane(63)
template<int C>
__device__ __forceinline__ float dpp_add_step(float x) {
  int t = __builtin_amdgcn_update_dpp(0, __float_as_int(x), C, 0xf, 0xf, true);
  return x + __int_as_float(t);
}
__device__ __forceinline__ float wave_sum64(float x) {
  x = dpp_add_step<0x111>(x);  // row_shr:1
  x = dpp_add_step<0x112>(x);  // row_shr:2
  x = dpp_add_step<0x114>(x);  // row_shr:4
  x = dpp_add_step<0x118>(x);  // row_shr:8
  x = dpp_add_step<0x142>(x);  // row_bcast:15
  x = dpp_add_step<0x143>(x);  // row_bcast:31
  return __int_as_float(__builtin_amdgcn_readlane(__float_as_int(x), 63));
}

// ---------------- prep: Wc = W_ih @ W_proj  [126][64], bc = b_ih + W_ih @ b_proj ----------------
__global__ void prep_kernel(const float* __restrict__ w_ih, const float* __restrict__ w_proj,
                            const float* __restrict__ b_proj, const float* __restrict__ b_ih,
                            float* __restrict__ Wc, float* __restrict__ bc) {
  int idx = blockIdx.x * 256 + threadIdx.x;
  if (idx < G3N * INN) {
    int j = idx / INN, i = idx % INN;
    float a = 0.0f;
    for (int k = 0; k < SDN; k++) a += w_ih[j * SDN + k] * w_proj[k * INN + i];
    Wc[idx] = a;
  }
  if (idx < G3N) {
    float a = b_ih[idx];
    for (int k = 0; k < SDN; k++) a += w_ih[idx * SDN + k] * b_proj[k];
    bc[idx] = a;
  }
}

// ---------------- gx GEMM: gxp[row][c] (GXS-padded rows), LDS-staged coalesced writes ----------------
__global__ __launch_bounds__(256)
void gx_gemm(const float* __restrict__ x, const float* __restrict__ Wc,
             const float* __restrict__ bc, float* __restrict__ gxp) {
  __shared__ __align__(16) float WcS[G3N * INN];   // 31.5 KB
  __shared__ float bcS[G3N + 2];                   // pad to 128 logical cols
  __shared__ float tileS[256 * 33];                // 33.8 KB, pad-33 stride
  const int tid = threadIdx.x;
  const float4* wc4 = (const float4*)Wc;
  float4* wcs4 = (float4*)WcS;
  for (int i = tid; i < G3N * INN / 4; i += 256) wcs4[i] = wc4[i];
  if (tid < G3N) bcS[tid] = bc[tid];
  __syncthreads();

  const size_t row0 = (size_t)blockIdx.x * 256;
  const size_t row = row0 + tid;
  v2f xr[INN / 2];
#pragma unroll
  for (int i = 0; i < INN / 4; i++) {
    float4 v = *reinterpret_cast<const float4*>(&x[row * INN + i * 4]);
    xr[2 * i]     = (v2f){v.x, v.y};
    xr[2 * i + 1] = (v2f){v.z, v.w};
  }

  for (int c0 = 0; c0 < GXS; c0 += 32) {
#pragma unroll
    for (int cc = 0; cc < 32; cc++) {
      int c = c0 + cc;
      float val = 0.0f;
      if (c < G3N) {
        const v2f* w = (const v2f*)&WcS[c * INN];
        v2f acc2 = (v2f){bcS[c], 0.0f};
#pragma unroll
        for (int i = 0; i < INN / 2; i++) acc2 = __builtin_elementwise_fma(w[i], xr[i], acc2);
        val = acc2.x + acc2.y;
      }
      tileS[tid * 33 + cc] = val;
    }
    __syncthreads();
    // coalesced write: 2048 float4 per tile, 8 per thread
#pragma unroll
    for (int i = 0; i < 8; i++) {
      int f = i * 256 + tid;      // float4 index
      int r = f >> 3;             // source row in tile
      int cc4 = (f & 7) * 4;
      float4 v = make_float4(tileS[r * 33 + cc4], tileS[r * 33 + cc4 + 1],
                             tileS[r * 33 + cc4 + 2], tileS[r * 33 + cc4 + 3]);
      *reinterpret_cast<float4*>(&gxp[(row0 + r) * GXS + c0 + cc4]) = v;
    }
    __syncthreads();
  }
}

// ---------------- recurrence: 8 waves/block, one wave per batch element ----------------
__global__ __launch_bounds__(512, 1)
void rec_kernel(const float* __restrict__ gxp,      // [BT][GXS]
                const float* __restrict__ w_hh,     // [126][42]
                const float* __restrict__ b_hh,     // [126]
                const float* __restrict__ w_bridge, // [128][42]
                const float* __restrict__ b_bridge, // [128]
                const float* __restrict__ w_jump,   // [128]
                const float* __restrict__ b_jump,   // [1]
                const float* __restrict__ w_gate,   // [128]
                const float* __restrict__ b_gate,   // [1]
                const float* __restrict__ theta,    // [1]
                float* __restrict__ hbuf,           // [B][T][HS]
                float* __restrict__ ptrbuf) {       // [B][T]
  const int wid = threadIdx.x >> 6;
  const int lane = threadIdx.x & 63;
  const int b = blockIdx.x * WPB + wid;
  const int jj = (lane < SDN) ? lane : (SDN - 1);  // clamped gate row
  const int r1 = lane + 64;

  __shared__ float2 JG_all[WPB][RINGN];            // 16 KB
  __shared__ __align__(16) float h_all[WPB][HS];   // 1.4 KB
  float2* JG = JG_all[wid];
  float* h_buf = h_all[wid];

  for (int i = lane; i < RINGN; i += 64) JG[i] = make_float2(0.f, 0.f);
  if (lane < HS) h_buf[lane] = 0.0f;

  // register-resident weight rows
  const v2f* whh2 = (const v2f*)w_hh;
  const v2f* wb2  = (const v2f*)w_bridge;
  v2f Whr[21], Whz[21], Whn[21], Wb0[21], Wb1[21];
#pragma unroll
  for (int k = 0; k < 21; k++) {
    Whr[k] = whh2[jj * 21 + k];
    Whz[k] = whh2[(jj + SDN) * 21 + k];
    Whn[k] = whh2[(jj + 2 * SDN) * 21 + k];
    Wb0[k] = wb2[lane * 21 + k];
    Wb1[k] = wb2[r1 * 21 + k];
  }
  const float bhr = b_hh[jj], bhz = b_hh[jj + SDN], bhn = b_hh[jj + 2 * SDN];
  const float bb0 = b_bridge[lane], bb1 = b_bridge[r1];
  const float wj0 = w_jump[lane], wj1 = w_jump[r1];
  const float wg0 = w_gate[lane], wg1 = w_gate[r1];
  const float bj = b_jump[0], bg = b_gate[0];

  v2f hv2[22];
#pragma unroll
  for (int k = 0; k < 22; k++) hv2[k] = (v2f){0.f, 0.f};
  float hprev = 0.0f;

  float ptr = wrap256(theta[0]);

  const float* gxr = gxp + (size_t)b * TN * GXS;
  const int o0 = jj, o1 = SDN + jj, o2 = 2 * SDN + jj;
  float* hb = hbuf + (size_t)b * TN * HS;
  float* pb = ptrbuf + (size_t)b * TN;

  // 2-deep prefetch: A = even t, B = odd t
  float pA0 = gxr[o0], pA1 = gxr[o1], pA2 = gxr[o2];
  float pB0 = gxr[GXS + o0], pB1 = gxr[GXS + o1], pB2 = gxr[GXS + o2];

  // prologue: taps at initial ptr (normalized) + pre-read of J/G window
  float wk[5]; float2 Vk[5];
  {
    int posk[5];
    taps_norm(ptr, posk, wk);
#pragma unroll
    for (int k = 0; k < 5; k++) Vk[k] = JG[posk[k]];
  }
  float pjprev = 0.f, pgprev = 0.f, S2prev = 0.f;

  auto STEP = [&](int t, float pgx0, float pgx1, float pgx2) {
    // ---- A: pointer chain ----
    float dotJ = 0.f, dotG = 0.f;
#pragma unroll
    for (int k = 0; k < 5; k++) { dotJ += wk[k] * Vk[k].x; dotG += wk[k] * Vk[k].y; }
    float Jv = fmaf(pjprev, S2prev, dotJ);
    float Gv = fmaf(pgprev, S2prev, dotG);
    float jump = 256.0f * sigm(Jv + bj);
    float gate = sigm(Gv + bg);
    float delta = wrap256(jump - ptr + 128.0f) - 128.0f;
    float ptr2 = wrap256(ptr + gate * delta);

    // taps(ptr2): unnormalized + inv
    float tbase = floorf(ptr2);
    float frac = ptr2 - tbase;
    int ib = (int)tbase;
    float e2[5], s = 0.f; int pos2[5];
#pragma unroll
    for (int k = 0; k < 5; k++) {
      float d = (float)(k - 2) - frac;
      e2[k] = __expf(-(d * d) * 0.125f);
      s += e2[k];
      pos2[k] = (ib + k - 2) & 255;
    }
    float inv2 = 1.0f / s;
    // pre-read J/G for next iteration (before this iter's ds_adds)
    float2 Vk2[5];
#pragma unroll
    for (int k = 0; k < 5; k++) Vk2[k] = JG[pos2[k]];
    float w2n[5], S2 = 0.f;
#pragma unroll
    for (int k = 0; k < 5; k++) { w2n[k] = e2[k] * inv2; S2 = fmaf(w2n[k], w2n[k], S2); }
    if (lane == 0) pb[t] = ptr2;

    // ---- B: h chain (2-way split accumulators) ----
    v2f ara = (v2f){bhr, 0.f}, aza = (v2f){bhz, 0.f}, ana = (v2f){bhn, 0.f};
    v2f arb = (v2f){0.f, 0.f}, azb = (v2f){0.f, 0.f}, anb = (v2f){0.f, 0.f};
#pragma unroll
    for (int k = 0; k < 21; k += 2) {
      v2f h2 = hv2[k];
      ara = __builtin_elementwise_fma(Whr[k], h2, ara);
      aza = __builtin_elementwise_fma(Whz[k], h2, aza);
      ana = __builtin_elementwise_fma(Whn[k], h2, ana);
    }
#pragma unroll
    for (int k = 1; k < 21; k += 2) {
      v2f h2 = hv2[k];
      arb = __builtin_elementwise_fma(Whr[k], h2, arb);
      azb = __builtin_elementwise_fma(Whz[k], h2, azb);
      anb = __builtin_elementwise_fma(Whn[k], h2, anb);
    }
    float ghr = (ara.x + arb.x) + (ara.y + arb.y);
    float ghz = (aza.x + azb.x) + (aza.y + azb.y);
    float ghn = (ana.x + anb.x) + (ana.y + anb.y);
    float rg = sigm(pgx0 + ghr);
    float zg = sigm(pgx1 + ghz);
    float ng = tanhfast(pgx2 + rg * ghn);
    float hn = (1.0f - zg) * ng + zg * hprev;
    hprev = hn;
    if (lane < SDN) {
      h_buf[lane] = hn;
      hb[(size_t)t * HS + lane] = hn;
    }
    // broadcast h' (uniform LDS reads)
#pragma unroll
    for (int i = 0; i < 11; i++) {
      float4 v = *reinterpret_cast<const float4*>(&h_buf[i * 4]);
      hv2[2 * i]     = (v2f){v.x, v.y};
      hv2[2 * i + 1] = (v2f){v.z, v.w};
    }

    // u = tanh(Wb h' + bb), dims lane, lane+64 (2-way split)
    v2f a0a = (v2f){bb0, 0.f}, a1a = (v2f){bb1, 0.f};
    v2f a0b = (v2f){0.f, 0.f}, a1b = (v2f){0.f, 0.f};
#pragma unroll
    for (int k = 0; k < 21; k += 2) {
      v2f h2 = hv2[k];
      a0a = __builtin_elementwise_fma(Wb0[k], h2, a0a);
      a1a = __builtin_elementwise_fma(Wb1[k], h2, a1a);
    }
#pragma unroll
    for (int k = 1; k < 21; k += 2) {
      v2f h2 = hv2[k];
      a0b = __builtin_elementwise_fma(Wb0[k], h2, a0b);
      a1b = __builtin_elementwise_fma(Wb1[k], h2, a1b);
    }
    float u0 = tanhfast((a0a.x + a0b.x) + (a0a.y + a0b.y));
    float u1 = tanhfast((a1a.x + a1b.x) + (a1a.y + a1b.y));

    float pjs = wave_sum64(u0 * wj0 + u1 * wj1);
    float pgs = wave_sum64(u0 * wg0 + u1 * wg1);

    // ---- C: J/G scatter-add (lanes 0..4) ----
    int p2sel = pos2[0]; float w2sel = w2n[0];
#pragma unroll
    for (int k = 1; k < 5; k++) {
      if (lane == k) { p2sel = pos2[k]; w2sel = w2n[k]; }
    }
    if (lane < 5) {
      atomicAdd(&JG[p2sel].x, w2sel * pjs);
      atomicAdd(&JG[p2sel].y, w2sel * pgs);
    }

    // rotate loop state
#pragma unroll
    for (int k = 0; k < 5; k++) { wk[k] = w2n[k]; Vk[k] = Vk2[k]; }
    S2prev = S2; pjprev = pjs; pgprev = pgs; ptr = ptr2;
  };

  for (int t = 0; t < TN; t += 2) {
    STEP(t, pA0, pA1, pA2);
    if (t + 2 < TN) {
      const float* g = gxr + (size_t)(t + 2) * GXS;
      pA0 = g[o0]; pA1 = g[o1]; pA2 = g[o2];
    }
    STEP(t + 1, pB0, pB1, pB2);
    if (t + 3 < TN) {
      const float* g = gxr + (size_t)(t + 3) * GXS;
      pB0 = g[o0]; pB1 = g[o1]; pB2 = g[o2];
    }
  }
}

// ---------------- r reconstruction: r[b] = sum_t c(t) * tanh(Wb h(t) + bb) ----------------
__global__ __launch_bounds__(64)
void rfinal_kernel(const float* __restrict__ hbuf, const float* __restrict__ ptrbuf,
                   const float* __restrict__ w_bridge, const float* __restrict__ b_bridge,
                   float* __restrict__ rbuf) {
  const int b = blockIdx.x;
  const int chunk = blockIdx.y;     // 4 chunks of 128 steps
  const int lane = threadIdx.x;
  const int t0 = chunk * 128;
  const int r1 = lane + 64;

  __shared__ float c_lds[128];

  const float* pb = ptrbuf + (size_t)b * TN;
  float ptrf = pb[TN - 1];
  int posf[5]; float wf[5];
  taps_norm(ptrf, posf, wf);

#pragma unroll
  for (int rr = 0; rr < 2; rr++) {
    int tt = rr * 64 + lane;
    int p2[5]; float w2[5];
    taps_norm(pb[t0 + tt], p2, w2);
    float c = 0.0f;
#pragma unroll
    for (int k = 0; k < 5; k++)
#pragma unroll
      for (int k2 = 0; k2 < 5; k2++)
        c += (posf[k] == p2[k2]) ? wf[k] * w2[k2] : 0.0f;
    c_lds[tt] = c;
  }
  __builtin_amdgcn_wave_barrier();

  const v2f* wb2 = (const v2f*)w_bridge;
  v2f Wb0[21], Wb1[21];
#pragma unroll
  for (int k = 0; k < 21; k++) { Wb0[k] = wb2[lane * 21 + k]; Wb1[k] = wb2[r1 * 21 + k]; }
  float bb0 = b_bridge[lane], bb1 = b_bridge[r1];

  float racc0 = 0.0f, racc1 = 0.0f;
  for (int tt = 0; tt < 128; tt++) {
    float ct = c_lds[tt];              // uniform across wave
    if (ct != 0.0f) {
      const float4* hp = (const float4*)(hbuf + ((size_t)b * TN + t0 + tt) * HS);
      v2f hx[22];
#pragma unroll
      for (int i = 0; i < 11; i++) {
        float4 v = hp[i];
        hx[2 * i]     = (v2f){v.x, v.y};
        hx[2 * i + 1] = (v2f){v.z, v.w};
      }
      v2f a0 = (v2f){bb0, 0.f}, a1 = (v2f){bb1, 0.f};
#pragma unroll
      for (int k = 0; k < 21; k++) {
        a0 = __builtin_elementwise_fma(Wb0[k], hx[k], a0);
        a1 = __builtin_elementwise_fma(Wb1[k], hx[k], a1);
      }
      racc0 += ct * tanhfast(a0.x + a0.y);
      racc1 += ct * tanhfast(a1.x + a1.y);
    }
  }
  atomicAdd(&rbuf[b * DD + lane], racc0);
  atomicAdd(&rbuf[b * DD + 64 + lane], racc1);
}

// ---------------- classifier: 4 batch rows per block; out = r @ w_cls.T + b_cls ----------------
__global__ __launch_bounds__(256)
void cls_kernel(const float* __restrict__ rbuf, const float* __restrict__ w_cls,
                const float* __restrict__ b_cls, float* __restrict__ out) {
  const int b0 = blockIdx.x * 4;
  const int tid = threadIdx.x;
  __shared__ __align__(16) float r[4 * DD];
  for (int i = tid; i < 4 * DD; i += 256) r[i] = rbuf[(size_t)b0 * DD + i];
  __syncthreads();

  for (int c = tid; c < NCN; c += 256) {
    float bcv = b_cls[c];
    float a0 = bcv, a1 = bcv, a2 = bcv, a3 = bcv;
    const float* wrow = &w_cls[(size_t)c * DD];
#pragma unroll
    for (int d4 = 0; d4 < DD / 4; d4++) {
      float4 wv = *reinterpret_cast<const float4*>(&wrow[d4 * 4]);
      float4 r0 = *reinterpret_cast<const float4*>(&r[0 * DD + d4 * 4]);
      float4 r1 = *reinterpret_cast<const float4*>(&r[1 * DD + d4 * 4]);
      float4 r2 = *reinterpret_cast<const float4*>(&r[2 * DD + d4 * 4]);
      float4 r3 = *reinterpret_cast<const float4*>(&r[3 * DD + d4 * 4]);
      a0 += wv.x * r0.x + wv.y * r0.y + wv.z * r0.z + wv.w * r0.w;
      a1 += wv.x * r1.x + wv.y * r1.y + wv.z * r1.z + wv.w * r1.w;
      a2 += wv.x * r2.x + wv.y * r2.y + wv.z * r2.z + wv.w * r2.w;
      a3 += wv.x * r3.x + wv.y * r3.y + wv.z * r3.z + wv.w * r3.w;
    }
    out[(size_t)(b0 + 0) * NCN + c] = a0;
    out[(size_t)(b0 + 1) * NCN + c] = a1;
    out[(size_t)(b0 + 2) * NCN + c] = a2;
    out[(size_t)(b0 + 3) * NCN + c] = a3;
  }
}

extern "C" void kernel_launch(void* const* d_in, const int* in_sizes, int n_in,
                              void* d_out, int out_size, void* d_ws, size_t ws_size,
                              hipStream_t stream) {
  const float* x        = (const float*)d_in[0];
  const float* theta    = (const float*)d_in[1];
  const float* w_proj   = (const float*)d_in[2];
  const float* b_proj   = (const float*)d_in[3];
  const float* w_ih     = (const float*)d_in[4];
  const float* w_hh     = (const float*)d_in[5];
  const float* b_ih     = (const float*)d_in[6];
  const float* b_hh     = (const float*)d_in[7];
  const float* w_bridge = (const float*)d_in[8];
  const float* b_bridge = (const float*)d_in[9];
  const float* w_jump   = (const float*)d_in[10];
  const float* b_jump   = (const float*)d_in[11];
  const float* w_gate   = (const float*)d_in[12];
  const float* b_gate   = (const float*)d_in[13];
  const float* w_cls    = (const float*)d_in[14];
  const float* b_cls    = (const float*)d_in[15];
  float* out = (float*)d_out;

  char* ws = (char*)d_ws;
  size_t off = 0;
  float* gxp    = (float*)(ws + off); off += (size_t)BT * GXS * 4;       // 134 MB
  float* hbuf   = (float*)(ws + off); off += (size_t)BN * TN * HS * 4;   // 46 MB
  float* ptrbuf = (float*)(ws + off); off += (size_t)BN * TN * 4;        // 1 MB
  float* rbuf   = (float*)(ws + off); off += (size_t)BN * DD * 4;        // 256 KB
  float* Wc     = (float*)(ws + off); off += (((size_t)G3N * INN * 4 + 255) & ~(size_t)255);
  float* bc     = (float*)(ws + off); off += 512;

  hipMemsetAsync(rbuf, 0, (size_t)BN * DD * 4, stream);
  prep_kernel<<<32, 256, 0, stream>>>(w_ih, w_proj, b_proj, b_ih, Wc, bc);
  gx_gemm<<<BT / 256, 256, 0, stream>>>(x, Wc, bc, gxp);
  rec_kernel<<<BN / WPB, 64 * WPB, 0, stream>>>(gxp, w_hh, b_hh, w_bridge, b_bridge,
                                                w_jump, b_jump, w_gate, b_gate, theta, hbuf, ptrbuf);
  dim3 gfin(BN, 4);
  rfinal_kernel<<<gfin, 64, 0, stream>>>(hbuf, ptrbuf, w_bridge, b_bridge, rbuf);
  cls_kernel<<<BN / 4, 256, 0, stream>>>(rbuf, w_cls, b_cls, out);
}

// Round 8
// 1291.498 us; speedup vs baseline: 2.6919x; 2.6919x over previous
//
#include <hip/hip_runtime.h>
#include <hip/hip_bf16.h>
#include <cstdint>

#define RINGN 256
#define DD    128
#define SDN   42
#define G3N   126
#define INN   64
#define BN    512
#define TN    512
#define NCN   1000
#define HS    44          // padded h row stride (floats)
#define GXS   128         // padded gx row stride (floats) -> 512B rows
#define BT    (BN * TN)

typedef float v2f __attribute__((ext_vector_type(2)));
typedef float4 __attribute__((may_alias)) f4ma;
typedef float2 __attribute__((may_alias)) f2ma;

__device__ __forceinline__ float sigm(float x)    { return 1.0f / (1.0f + __expf(-x)); }
__device__ __forceinline__ float tanhfast(float x){ float e = __expf(2.0f * x); return 1.0f - 2.0f / (e + 1.0f); }
__device__ __forceinline__ float wrap256(float x) { return x - 256.0f * floorf(x * 0.00390625f); }

__device__ __forceinline__ void taps_norm(float p, int* pos, float* w) {
  float base = floorf(p);
  float frac = p - base;
  int ib = (int)base;
  float e[5];
  float s = 0.0f;
#pragma unroll
  for (int k = 0; k < 5; k++) {
    float d = (float)(k - 2) - frac;
    e[k] = __expf(-(d * d) * 0.125f);
    s += e[k];
    pos[k] = (ib + k - 2) & 255;
  }
  float inv = 1.0f / s;
#pragma unroll
  for (int k = 0; k < 5; k++) w[k] = e[k] * inv;
}

__device__ __forceinline__ void taps_s2(float p, int* pos, float* w, float& S2) {
  float base = floorf(p);
  float frac = p - base;
  int ib = (int)base;
  float e[5], s = 0.0f;
#pragma unroll
  for (int k = 0; k < 5; k++) {
    float d = (float)(k - 2) - frac;
    e[k] = __expf(-(d * d) * 0.125f);
    s += e[k];
    pos[k] = (ib + k - 2) & 255;
  }
  float inv = 1.0f / s;
  S2 = 0.0f;
#pragma unroll
  for (int k = 0; k < 5; k++) { w[k] = e[k] * inv; S2 = fmaf(w[k], w[k], S2); }
}

// DPP full-wave sum, result broadcast via readlane(63)
template<int C>
__device__ __forceinline__ float dpp_add_step(float x) {
  int t = __builtin_amdgcn_update_dpp(0, __float_as_int(x), C, 0xf, 0xf, true);
  return x + __int_as_float(t);
}
__device__ __forceinline__ float wave_sum64(float x) {
  x = dpp_add_step<0x111>(x);
  x = dpp_add_step<0x112>(x);
  x = dpp_add_step<0x114>(x);
  x = dpp_add_step<0x118>(x);
  x = dpp_add_step<0x142>(x);
  x = dpp_add_step<0x143>(x);
  return __int_as_float(__builtin_amdgcn_readlane(__float_as_int(x), 63));
}

// ---------------- prep ----------------
__global__ void prep_kernel(const float* __restrict__ w_ih, const float* __restrict__ w_proj,
                            const float* __restrict__ b_proj, const float* __restrict__ b_ih,
                            float* __restrict__ Wc, float* __restrict__ bc) {
  int idx = blockIdx.x * 256 + threadIdx.x;
  if (idx < G3N * INN) {
    int j = idx / INN, i = idx % INN;
    float a = 0.0f;
    for (int k = 0; k < SDN; k++) a += w_ih[j * SDN + k] * w_proj[k * INN + i];
    Wc[idx] = a;
  }
  if (idx < G3N) {
    float a = b_ih[idx];
    for (int k = 0; k < SDN; k++) a += w_ih[idx * SDN + k] * b_proj[k];
    bc[idx] = a;
  }
}

// ---------------- gx GEMM: gxp[row][c] padded rows, LDS-staged coalesced writes ----------------
// NOTE: inner-loop accumulation MUST stay the v2f single-accumulator form (bit-identical
// to the passing rounds). The pointer recurrence is discretely chaotic: re-associating
// this sum flips floor() buckets downstream and diverges trajectories (rounds 6/7).
__global__ __launch_bounds__(256)
void gx_gemm(const float* __restrict__ x, const float* __restrict__ Wc,
             const float* __restrict__ bc, float* __restrict__ gxp) {
  __shared__ __align__(16) float WcS[G3N * INN];
  __shared__ float bcS[G3N + 2];
  __shared__ float tileS[256 * 33];
  const int tid = threadIdx.x;
  const float4* wc4 = (const float4*)Wc;
  float4* wcs4 = (float4*)WcS;
  for (int i = tid; i < G3N * INN / 4; i += 256) wcs4[i] = wc4[i];
  if (tid < G3N) bcS[tid] = bc[tid];
  __syncthreads();

  const size_t row0 = (size_t)blockIdx.x * 256;
  const size_t row = row0 + tid;
  v2f xr[INN / 2];
#pragma unroll
  for (int i = 0; i < INN / 4; i++) {
    float4 v = *reinterpret_cast<const float4*>(&x[row * INN + i * 4]);
    xr[2 * i]     = (v2f){v.x, v.y};
    xr[2 * i + 1] = (v2f){v.z, v.w};
  }

  for (int c0 = 0; c0 < GXS; c0 += 32) {
#pragma unroll
    for (int cc = 0; cc < 32; cc++) {
      int c = c0 + cc;
      float val = 0.0f;
      if (c < G3N) {
        const v2f* w = (const v2f*)&WcS[c * INN];
        v2f acc2 = (v2f){bcS[c], 0.0f};
#pragma unroll
        for (int i = 0; i < INN / 2; i++) acc2 = __builtin_elementwise_fma(w[i], xr[i], acc2);
        val = acc2.x + acc2.y;
      }
      tileS[tid * 33 + cc] = val;
    }
    __syncthreads();
#pragma unroll
    for (int i = 0; i < 8; i++) {
      int f = i * 256 + tid;
      int r = f >> 3;
      int cc4 = (f & 7) * 4;
      float4 v = make_float4(tileS[r * 33 + cc4], tileS[r * 33 + cc4 + 1],
                             tileS[r * 33 + cc4 + 2], tileS[r * 33 + cc4 + 3]);
      *reinterpret_cast<float4*>(&gxp[(row0 + r) * GXS + c0 + cc4]) = v;
    }
    __syncthreads();
  }
}

// helpers operating on register arrays (fully inlined, static indices)
__device__ __forceinline__ void gru_mv(const v2f* Whr, const v2f* Whz, const v2f* Whn,
                                       const v2f* hv, float bhr, float bhz, float bhn,
                                       float& ghr, float& ghz, float& ghn) {
  v2f ara = (v2f){bhr, 0.f}, aza = (v2f){bhz, 0.f}, ana = (v2f){bhn, 0.f};
  v2f arb = (v2f){0.f, 0.f}, azb = (v2f){0.f, 0.f}, anb = (v2f){0.f, 0.f};
#pragma unroll
  for (int k = 0; k < 21; k += 2) {
    v2f h2 = hv[k];
    ara = __builtin_elementwise_fma(Whr[k], h2, ara);
    aza = __builtin_elementwise_fma(Whz[k], h2, aza);
    ana = __builtin_elementwise_fma(Whn[k], h2, ana);
  }
#pragma unroll
  for (int k = 1; k < 21; k += 2) {
    v2f h2 = hv[k];
    arb = __builtin_elementwise_fma(Whr[k], h2, arb);
    azb = __builtin_elementwise_fma(Whz[k], h2, azb);
    anb = __builtin_elementwise_fma(Whn[k], h2, anb);
  }
  ghr = (ara.x + arb.x) + (ara.y + arb.y);
  ghz = (aza.x + azb.x) + (aza.y + azb.y);
  ghn = (ana.x + anb.x) + (ana.y + anb.y);
}

__device__ __forceinline__ void bridge_mv(const v2f* Wb0, const v2f* Wb1, const v2f* hv,
                                          float bb0, float bb1, float& u0, float& u1) {
  v2f a0a = (v2f){bb0, 0.f}, a1a = (v2f){bb1, 0.f};
  v2f a0b = (v2f){0.f, 0.f}, a1b = (v2f){0.f, 0.f};
#pragma unroll
  for (int k = 0; k < 21; k += 2) {
    v2f h2 = hv[k];
    a0a = __builtin_elementwise_fma(Wb0[k], h2, a0a);
    a1a = __builtin_elementwise_fma(Wb1[k], h2, a1a);
  }
#pragma unroll
  for (int k = 1; k < 21; k += 2) {
    v2f h2 = hv[k];
    a0b = __builtin_elementwise_fma(Wb0[k], h2, a0b);
    a1b = __builtin_elementwise_fma(Wb1[k], h2, a1b);
  }
  u0 = tanhfast((a0a.x + a0b.x) + (a0a.y + a0b.y));
  u1 = tanhfast((a1a.x + a1b.x) + (a1a.y + a1b.y));
}

// ---------------- recurrence: ONE wave per block, TWO sequences per wave (ILP) ----------------
__global__ __launch_bounds__(64, 1)
void rec_kernel(const float* __restrict__ gxp,      // [BT][GXS]
                const float* __restrict__ w_hh, const float* __restrict__ b_hh,
                const float* __restrict__ w_bridge, const float* __restrict__ b_bridge,
                const float* __restrict__ w_jump, const float* __restrict__ b_jump,
                const float* __restrict__ w_gate, const float* __restrict__ b_gate,
                const float* __restrict__ theta,
                float* __restrict__ hbuf, float* __restrict__ ptrbuf) {
  const int lane = threadIdx.x;
  const int jj = (lane < SDN) ? lane : (SDN - 1);
  const int r1 = lane + 64;
  const int bA = blockIdx.x * 2;
  const int bB = bA + 1;

  __shared__ float2 JGA[RINGN];
  __shared__ float2 JGB[RINGN];
  __shared__ __align__(16) float hlA[64];
  __shared__ __align__(16) float hlB[64];

  for (int i = lane; i < RINGN; i += 64) { JGA[i] = make_float2(0.f, 0.f); JGB[i] = make_float2(0.f, 0.f); }
  hlA[lane] = 0.0f; hlB[lane] = 0.0f;
  __builtin_amdgcn_wave_barrier();
  asm volatile("" ::: "memory");   // LDS init visible before pre-reads below

  // shared register-resident weights (the reason both seqs live on one wave)
  const v2f* whh2 = (const v2f*)w_hh;
  const v2f* wb2  = (const v2f*)w_bridge;
  v2f Whr[21], Whz[21], Whn[21], Wb0[21], Wb1[21];
#pragma unroll
  for (int k = 0; k < 21; k++) {
    Whr[k] = whh2[jj * 21 + k];
    Whz[k] = whh2[(jj + SDN) * 21 + k];
    Whn[k] = whh2[(jj + 2 * SDN) * 21 + k];
    Wb0[k] = wb2[lane * 21 + k];
    Wb1[k] = wb2[r1 * 21 + k];
  }
  const float bhr = b_hh[jj], bhz = b_hh[jj + SDN], bhn = b_hh[jj + 2 * SDN];
  const float bb0 = b_bridge[lane], bb1 = b_bridge[r1];
  const float wj0 = w_jump[lane], wj1 = w_jump[r1];
  const float wg0 = w_gate[lane], wg1 = w_gate[r1];
  const float bj = b_jump[0], bg = b_gate[0];

  // per-seq state
  v2f hvA[21], hvB[21];
#pragma unroll
  for (int k = 0; k < 21; k++) { hvA[k] = (v2f){0.f, 0.f}; hvB[k] = (v2f){0.f, 0.f}; }
  float hpA = 0.f, hpB = 0.f;
  float ptrA = wrap256(theta[0]), ptrB = ptrA;

  const float* gxA = gxp + (size_t)bA * TN * GXS;
  const float* gxB = gxp + (size_t)bB * TN * GXS;
  float* hbA = hbuf + (size_t)bA * TN * HS;
  float* hbB = hbuf + (size_t)bB * TN * HS;
  float* pbA = ptrbuf + (size_t)bA * TN;
  float* pbB = ptrbuf + (size_t)bB * TN;
  const int o0 = jj, o1 = SDN + jj, o2 = 2 * SDN + jj;

  float cgA0 = gxA[o0], cgA1 = gxA[o1], cgA2 = gxA[o2];
  float cgB0 = gxB[o0], cgB1 = gxB[o1], cgB2 = gxB[o2];
  float ngA0 = 0.f, ngA1 = 0.f, ngA2 = 0.f, ngB0 = 0.f, ngB1 = 0.f, ngB2 = 0.f;

  float wkA[5], wkB[5]; float2 VkA[5], VkB[5];
  {
    int pk[5];
    taps_norm(ptrA, pk, wkA);
#pragma unroll
    for (int k = 0; k < 5; k++) VkA[k] = JGA[pk[k]];
  }
  {
    int pk[5];
    taps_norm(ptrB, pk, wkB);
#pragma unroll
    for (int k = 0; k < 5; k++) VkB[k] = JGB[pk[k]];
  }
  float pjpA = 0.f, pgpA = 0.f, S2pA = 0.f;
  float pjpB = 0.f, pgpB = 0.f, S2pB = 0.f;

  for (int t = 0; t < TN; t++) {
    // ---- prefetch gx(t+1) (consumed next iteration: full step of latency cover) ----
    if (t + 1 < TN) {
      const float* gA = gxA + (size_t)(t + 1) * GXS;
      const float* gB = gxB + (size_t)(t + 1) * GXS;
      ngA0 = gA[o0]; ngA1 = gA[o1]; ngA2 = gA[o2];
      ngB0 = gB[o0]; ngB1 = gB[o1]; ngB2 = gB[o2];
    }

    // ---- pointer chains (A and B independent) ----
    float dJA = 0.f, dGA = 0.f, dJB = 0.f, dGB = 0.f;
#pragma unroll
    for (int k = 0; k < 5; k++) {
      dJA += wkA[k] * VkA[k].x; dGA += wkA[k] * VkA[k].y;
      dJB += wkB[k] * VkB[k].x; dGB += wkB[k] * VkB[k].y;
    }
    float JvA = fmaf(pjpA, S2pA, dJA), GvA = fmaf(pgpA, S2pA, dGA);
    float JvB = fmaf(pjpB, S2pB, dJB), GvB = fmaf(pgpB, S2pB, dGB);
    float jmpA = 256.0f * sigm(JvA + bj), gtA = sigm(GvA + bg);
    float jmpB = 256.0f * sigm(JvB + bj), gtB = sigm(GvB + bg);
    float ptr2A = wrap256(ptrA + gtA * (wrap256(jmpA - ptrA + 128.0f) - 128.0f));
    float ptr2B = wrap256(ptrB + gtB * (wrap256(jmpB - ptrB + 128.0f) - 128.0f));

    int p2A[5], p2B[5]; float w2A[5], w2B[5], S2A, S2B;
    taps_s2(ptr2A, p2A, w2A, S2A);
    taps_s2(ptr2B, p2B, w2B, S2B);
    // pre-read next windows BEFORE this iter's scatter (exact S2*pj correction next iter)
    float2 V2A[5], V2B[5];
#pragma unroll
    for (int k = 0; k < 5; k++) { V2A[k] = JGA[p2A[k]]; V2B[k] = JGB[p2B[k]]; }

    if (lane == 0) pbA[t] = ptr2A;
    else if (lane == 1) pbB[t] = ptr2B;

    // ---- GRU matvecs + gates ----
    float ghrA, ghzA, ghnA, ghrB, ghzB, ghnB;
    gru_mv(Whr, Whz, Whn, hvA, bhr, bhz, bhn, ghrA, ghzA, ghnA);
    gru_mv(Whr, Whz, Whn, hvB, bhr, bhz, bhn, ghrB, ghzB, ghnB);
    float rgA = sigm(cgA0 + ghrA), zgA = sigm(cgA1 + ghzA);
    float ngateA = tanhfast(cgA2 + rgA * ghnA);
    float hnA = (1.0f - zgA) * ngateA + zgA * hpA;
    float rgB = sigm(cgB0 + ghrB), zgB = sigm(cgB1 + ghzB);
    float ngateB = tanhfast(cgB2 + rgB * ghnB);
    float hnB = (1.0f - zgB) * ngateB + zgB * hpB;
    hpA = hnA; hpB = hnB;

    if (lane < SDN) {
      hlA[lane] = hnA;
      hlB[lane] = hnB;
      hbA[(size_t)t * HS + lane] = hnA;
      hbB[(size_t)t * HS + lane] = hnB;
    }
    __builtin_amdgcn_wave_barrier();
    asm volatile("" ::: "memory");   // forbid hoisting the broadcast reads above the stores

    // broadcast h' (uniform LDS reads), 42 floats each
#pragma unroll
    for (int i = 0; i < 10; i++) {
      float4 vA = *(const f4ma*)(&hlA[i * 4]);
      float4 vB = *(const f4ma*)(&hlB[i * 4]);
      hvA[2 * i]     = (v2f){vA.x, vA.y};
      hvA[2 * i + 1] = (v2f){vA.z, vA.w};
      hvB[2 * i]     = (v2f){vB.x, vB.y};
      hvB[2 * i + 1] = (v2f){vB.z, vB.w};
    }
    {
      float2 vA = *(const f2ma*)(&hlA[40]);
      float2 vB = *(const f2ma*)(&hlB[40]);
      hvA[20] = (v2f){vA.x, vA.y};
      hvB[20] = (v2f){vB.x, vB.y};
    }

    // ---- bridge matvecs + projections ----
    float u0A, u1A, u0B, u1B;
    bridge_mv(Wb0, Wb1, hvA, bb0, bb1, u0A, u1A);
    bridge_mv(Wb0, Wb1, hvB, bb0, bb1, u0B, u1B);
    float pjA = wave_sum64(u0A * wj0 + u1A * wj1);
    float pgA = wave_sum64(u0A * wg0 + u1A * wg1);
    float pjB = wave_sum64(u0B * wj0 + u1B * wj1);
    float pgB = wave_sum64(u0B * wg0 + u1B * wg1);

    // ---- J/G scatter: lanes 0..4 -> A, lanes 5..9 -> B ----
    int selk = (lane < 5) ? lane : (lane - 5);
    int pA_ = p2A[0]; float wA_ = w2A[0];
    int pB_ = p2B[0]; float wB_ = w2B[0];
#pragma unroll
    for (int k = 1; k < 5; k++) {
      if (selk == k) { pA_ = p2A[k]; wA_ = w2A[k]; pB_ = p2B[k]; wB_ = w2B[k]; }
    }
    if (lane < 5) {
      atomicAdd(&JGA[pA_].x, wA_ * pjA);
      atomicAdd(&JGA[pA_].y, wA_ * pgA);
    } else if (lane < 10) {
      atomicAdd(&JGB[pB_].x, wB_ * pjB);
      atomicAdd(&JGB[pB_].y, wB_ * pgB);
    }

    // ---- rotate ----
#pragma unroll
    for (int k = 0; k < 5; k++) { wkA[k] = w2A[k]; VkA[k] = V2A[k]; wkB[k] = w2B[k]; VkB[k] = V2B[k]; }
    S2pA = S2A; pjpA = pjA; pgpA = pgA; ptrA = ptr2A;
    S2pB = S2B; pjpB = pjB; pgpB = pgB; ptrB = ptr2B;
    cgA0 = ngA0; cgA1 = ngA1; cgA2 = ngA2;
    cgB0 = ngB0; cgB1 = ngB1; cgB2 = ngB2;
  }
}

// ---------------- r reconstruction ----------------
__global__ __launch_bounds__(64)
void rfinal_kernel(const float* __restrict__ hbuf, const float* __restrict__ ptrbuf,
                   const float* __restrict__ w_bridge, const float* __restrict__ b_bridge,
                   float* __restrict__ rbuf) {
  const int b = blockIdx.x;
  const int chunk = blockIdx.y;
  const int lane = threadIdx.x;
  const int t0 = chunk * 128;
  const int r1 = lane + 64;

  __shared__ float c_lds[128];

  const float* pb = ptrbuf + (size_t)b * TN;
  float ptrf = pb[TN - 1];
  int posf[5]; float wf[5];
  taps_norm(ptrf, posf, wf);

#pragma unroll
  for (int rr = 0; rr < 2; rr++) {
    int tt = rr * 64 + lane;
    int p2[5]; float w2[5];
    taps_norm(pb[t0 + tt], p2, w2);
    float c = 0.0f;
#pragma unroll
    for (int k = 0; k < 5; k++)
#pragma unroll
      for (int k2 = 0; k2 < 5; k2++)
        c += (posf[k] == p2[k2]) ? wf[k] * w2[k2] : 0.0f;
    c_lds[tt] = c;
  }
  __builtin_amdgcn_wave_barrier();
  asm volatile("" ::: "memory");

  const v2f* wb2 = (const v2f*)w_bridge;
  v2f Wb0[21], Wb1[21];
#pragma unroll
  for (int k = 0; k < 21; k++) { Wb0[k] = wb2[lane * 21 + k]; Wb1[k] = wb2[r1 * 21 + k]; }
  float bb0 = b_bridge[lane], bb1 = b_bridge[r1];

  float racc0 = 0.0f, racc1 = 0.0f;
  for (int tt = 0; tt < 128; tt++) {
    float ct = c_lds[tt];
    if (ct != 0.0f) {
      const f4ma* hp = (const f4ma*)(hbuf + ((size_t)b * TN + t0 + tt) * HS);
      v2f hx[22];
#pragma unroll
      for (int i = 0; i < 11; i++) {
        float4 v = hp[i];
        hx[2 * i]     = (v2f){v.x, v.y};
        hx[2 * i + 1] = (v2f){v.z, v.w};
      }
      v2f a0 = (v2f){bb0, 0.f}, a1 = (v2f){bb1, 0.f};
#pragma unroll
      for (int k = 0; k < 21; k++) {
        a0 = __builtin_elementwise_fma(Wb0[k], hx[k], a0);
        a1 = __builtin_elementwise_fma(Wb1[k], hx[k], a1);
      }
      racc0 += ct * tanhfast(a0.x + a0.y);
      racc1 += ct * tanhfast(a1.x + a1.y);
    }
  }
  atomicAdd(&rbuf[b * DD + lane], racc0);
  atomicAdd(&rbuf[b * DD + 64 + lane], racc1);
}

// ---------------- classifier ----------------
__global__ __launch_bounds__(256)
void cls_kernel(const float* __restrict__ rbuf, const float* __restrict__ w_cls,
                const float* __restrict__ b_cls, float* __restrict__ out) {
  const int b0 = blockIdx.x * 4;
  const int tid = threadIdx.x;
  __shared__ __align__(16) float r[4 * DD];
  for (int i = tid; i < 4 * DD; i += 256) r[i] = rbuf[(size_t)b0 * DD + i];
  __syncthreads();

  for (int c = tid; c < NCN; c += 256) {
    float bcv = b_cls[c];
    float a0 = bcv, a1 = bcv, a2 = bcv, a3 = bcv;
    const float* wrow = &w_cls[(size_t)c * DD];
#pragma unroll
    for (int d4 = 0; d4 < DD / 4; d4++) {
      float4 wv = *reinterpret_cast<const float4*>(&wrow[d4 * 4]);
      float4 r0 = *(const f4ma*)(&r[0 * DD + d4 * 4]);
      float4 r1 = *(const f4ma*)(&r[1 * DD + d4 * 4]);
      float4 r2 = *(const f4ma*)(&r[2 * DD + d4 * 4]);
      float4 r3 = *(const f4ma*)(&r[3 * DD + d4 * 4]);
      a0 += wv.x * r0.x + wv.y * r0.y + wv.z * r0.z + wv.w * r0.w;
      a1 += wv.x * r1.x + wv.y * r1.y + wv.z * r1.z + wv.w * r1.w;
      a2 += wv.x * r2.x + wv.y * r2.y + wv.z * r2.z + wv.w * r2.w;
      a3 += wv.x * r3.x + wv.y * r3.y + wv.z * r3.z + wv.w * r3.w;
    }
    out[(size_t)(b0 + 0) * NCN + c] = a0;
    out[(size_t)(b0 + 1) * NCN + c] = a1;
    out[(size_t)(b0 + 2) * NCN + c] = a2;
    out[(size_t)(b0 + 3) * NCN + c] = a3;
  }
}

extern "C" void kernel_launch(void* const* d_in, const int* in_sizes, int n_in,
                              void* d_out, int out_size, void* d_ws, size_t ws_size,
                              hipStream_t stream) {
  const float* x        = (const float*)d_in[0];
  const float* theta    = (const float*)d_in[1];
  const float* w_proj   = (const float*)d_in[2];
  const float* b_proj   = (const float*)d_in[3];
  const float* w_ih     = (const float*)d_in[4];
  const float* w_hh     = (const float*)d_in[5];
  const float* b_ih     = (const float*)d_in[6];
  const float* b_hh     = (const float*)d_in[7];
  const float* w_bridge = (const float*)d_in[8];
  const float* b_bridge = (const float*)d_in[9];
  const float* w_jump   = (const float*)d_in[10];
  const float* b_jump   = (const float*)d_in[11];
  const float* w_gate   = (const float*)d_in[12];
  const float* b_gate   = (const float*)d_in[13];
  const float* w_cls    = (const float*)d_in[14];
  const float* b_cls    = (const float*)d_in[15];
  float* out = (float*)d_out;

  char* ws = (char*)d_ws;
  size_t off = 0;
  float* gxp    = (float*)(ws + off); off += (size_t)BT * GXS * 4;
  float* hbuf   = (float*)(ws + off); off += (size_t)BN * TN * HS * 4;
  float* ptrbuf = (float*)(ws + off); off += (size_t)BN * TN * 4;
  float* rbuf   = (float*)(ws + off); off += (size_t)BN * DD * 4;
  float* Wc     = (float*)(ws + off); off += (((size_t)G3N * INN * 4 + 255) & ~(size_t)255);
  float* bc     = (float*)(ws + off); off += 512;

  hipMemsetAsync(rbuf, 0, (size_t)BN * DD * 4, stream);
  prep_kernel<<<32, 256, 0, stream>>>(w_ih, w_proj, b_proj, b_ih, Wc, bc);
  gx_gemm<<<BT / 256, 256, 0, stream>>>(x, Wc, bc, gxp);
  rec_kernel<<<BN / 2, 64, 0, stream>>>(gxp, w_hh, b_hh, w_bridge, b_bridge,
                                        w_jump, b_jump, w_gate, b_gate, theta, hbuf, ptrbuf);
  dim3 gfin(BN, 4);
  rfinal_kernel<<<gfin, 64, 0, stream>>>(hbuf, ptrbuf, w_bridge, b_bridge, rbuf);
  cls_kernel<<<BN / 4, 256, 0, stream>>>(rbuf, w_cls, b_cls, out);
}

// Round 9
// 702.885 us; speedup vs baseline: 4.9461x; 1.8374x over previous
//
#include <hip/hip_runtime.h>
#include <hip/hip_bf16.h>
#include <cstdint>

#define RINGN 256
#define DD    128
#define SDN   42
#define G3N   126
#define INN   64
#define BN    512
#define TN    512
#define NCN   1000
#define HS    44          // padded h row stride (floats)
#define GXS   128         // padded gx row stride (floats) -> 512B rows
#define BT    (BN * TN)

typedef float v2f __attribute__((ext_vector_type(2)));
typedef float4 __attribute__((may_alias)) f4ma;
typedef float2 __attribute__((may_alias)) f2ma;

__device__ __forceinline__ float sigm(float x)    { return 1.0f / (1.0f + __expf(-x)); }
__device__ __forceinline__ float tanhfast(float x){ float e = __expf(2.0f * x); return 1.0f - 2.0f / (e + 1.0f); }
__device__ __forceinline__ float wrap256(float x) { return x - 256.0f * floorf(x * 0.00390625f); }

__device__ __forceinline__ void taps_norm(float p, int* pos, float* w) {
  float base = floorf(p);
  float frac = p - base;
  int ib = (int)base;
  float e[5];
  float s = 0.0f;
#pragma unroll
  for (int k = 0; k < 5; k++) {
    float d = (float)(k - 2) - frac;
    e[k] = __expf(-(d * d) * 0.125f);
    s += e[k];
    pos[k] = (ib + k - 2) & 255;
  }
  float inv = 1.0f / s;
#pragma unroll
  for (int k = 0; k < 5; k++) w[k] = e[k] * inv;
}

// DPP full-wave sum, result broadcast via readlane(63)
template<int C>
__device__ __forceinline__ float dpp_add_step(float x) {
  int t = __builtin_amdgcn_update_dpp(0, __float_as_int(x), C, 0xf, 0xf, true);
  return x + __int_as_float(t);
}
__device__ __forceinline__ float wave_sum64(float x) {
  x = dpp_add_step<0x111>(x);  // row_shr:1
  x = dpp_add_step<0x112>(x);  // row_shr:2
  x = dpp_add_step<0x114>(x);  // row_shr:4
  x = dpp_add_step<0x118>(x);  // row_shr:8
  x = dpp_add_step<0x142>(x);  // row_bcast:15
  x = dpp_add_step<0x143>(x);  // row_bcast:31
  return __int_as_float(__builtin_amdgcn_readlane(__float_as_int(x), 63));
}

// ---------------- prep ----------------
__global__ void prep_kernel(const float* __restrict__ w_ih, const float* __restrict__ w_proj,
                            const float* __restrict__ b_proj, const float* __restrict__ b_ih,
                            float* __restrict__ Wc, float* __restrict__ bc) {
  int idx = blockIdx.x * 256 + threadIdx.x;
  if (idx < G3N * INN) {
    int j = idx / INN, i = idx % INN;
    float a = 0.0f;
    for (int k = 0; k < SDN; k++) a += w_ih[j * SDN + k] * w_proj[k * INN + i];
    Wc[idx] = a;
  }
  if (idx < G3N) {
    float a = b_ih[idx];
    for (int k = 0; k < SDN; k++) a += w_ih[idx * SDN + k] * b_proj[k];
    bc[idx] = a;
  }
}

// ---------------- gx GEMM: gxp[row][c] padded rows, LDS-staged coalesced writes ----------------
// NOTE: inner-loop accumulation MUST stay the v2f single-accumulator form (bit-identical
// to the passing rounds). The pointer recurrence is discretely chaotic: re-associating
// this sum flips floor() buckets downstream and diverges trajectories (rounds 6/7).
__global__ __launch_bounds__(256)
void gx_gemm(const float* __restrict__ x, const float* __restrict__ Wc,
             const float* __restrict__ bc, float* __restrict__ gxp) {
  __shared__ __align__(16) float WcS[G3N * INN];
  __shared__ float bcS[G3N + 2];
  __shared__ float tileS[256 * 33];
  const int tid = threadIdx.x;
  const float4* wc4 = (const float4*)Wc;
  float4* wcs4 = (float4*)WcS;
  for (int i = tid; i < G3N * INN / 4; i += 256) wcs4[i] = wc4[i];
  if (tid < G3N) bcS[tid] = bc[tid];
  __syncthreads();

  const size_t row0 = (size_t)blockIdx.x * 256;
  const size_t row = row0 + tid;
  v2f xr[INN / 2];
#pragma unroll
  for (int i = 0; i < INN / 4; i++) {
    float4 v = *reinterpret_cast<const float4*>(&x[row * INN + i * 4]);
    xr[2 * i]     = (v2f){v.x, v.y};
    xr[2 * i + 1] = (v2f){v.z, v.w};
  }

  for (int c0 = 0; c0 < GXS; c0 += 32) {
#pragma unroll
    for (int cc = 0; cc < 32; cc++) {
      int c = c0 + cc;
      float val = 0.0f;
      if (c < G3N) {
        const v2f* w = (const v2f*)&WcS[c * INN];
        v2f acc2 = (v2f){bcS[c], 0.0f};
#pragma unroll
        for (int i = 0; i < INN / 2; i++) acc2 = __builtin_elementwise_fma(w[i], xr[i], acc2);
        val = acc2.x + acc2.y;
      }
      tileS[tid * 33 + cc] = val;
    }
    __syncthreads();
#pragma unroll
    for (int i = 0; i < 8; i++) {
      int f = i * 256 + tid;
      int r = f >> 3;
      int cc4 = (f & 7) * 4;
      float4 v = make_float4(tileS[r * 33 + cc4], tileS[r * 33 + cc4 + 1],
                             tileS[r * 33 + cc4 + 2], tileS[r * 33 + cc4 + 3]);
      *reinterpret_cast<float4*>(&gxp[(row0 + r) * GXS + c0 + cc4]) = v;
    }
    __syncthreads();
  }
}

// ---------------- recurrence: one wave per batch element (round-4 arithmetic, verbatim) ----------------
__global__ __launch_bounds__(64, 1)
void rec_kernel(const float* __restrict__ gxp,      // [BT][GXS]
                const float* __restrict__ w_hh,     // [126][42]
                const float* __restrict__ b_hh,     // [126]
                const float* __restrict__ w_bridge, // [128][42]
                const float* __restrict__ b_bridge, // [128]
                const float* __restrict__ w_jump,   // [128]
                const float* __restrict__ b_jump,   // [1]
                const float* __restrict__ w_gate,   // [128]
                const float* __restrict__ b_gate,   // [1]
                const float* __restrict__ theta,    // [1]
                float* __restrict__ hbuf,           // [B][T][HS]
                float* __restrict__ ptrbuf) {       // [B][T]
  const int b = blockIdx.x;
  const int lane = threadIdx.x;
  const int jj = (lane < SDN) ? lane : (SDN - 1);  // clamped gate row
  const int r1 = lane + 64;

  __shared__ float2 JG[RINGN];
  __shared__ __align__(16) float h_buf[HS];

  for (int i = lane; i < RINGN; i += 64) JG[i] = make_float2(0.f, 0.f);
  if (lane < HS) h_buf[lane] = 0.0f;
  __builtin_amdgcn_wave_barrier();
  asm volatile("" ::: "memory");

  // register-resident weight rows
  const v2f* whh2 = (const v2f*)w_hh;
  const v2f* wb2  = (const v2f*)w_bridge;
  v2f Whr[21], Whz[21], Whn[21], Wb0[21], Wb1[21];
#pragma unroll
  for (int k = 0; k < 21; k++) {
    Whr[k] = whh2[jj * 21 + k];
    Whz[k] = whh2[(jj + SDN) * 21 + k];
    Whn[k] = whh2[(jj + 2 * SDN) * 21 + k];
    Wb0[k] = wb2[lane * 21 + k];
    Wb1[k] = wb2[r1 * 21 + k];
  }
  const float bhr = b_hh[jj], bhz = b_hh[jj + SDN], bhn = b_hh[jj + 2 * SDN];
  const float bb0 = b_bridge[lane], bb1 = b_bridge[r1];
  const float wj0 = w_jump[lane], wj1 = w_jump[r1];
  const float wg0 = w_gate[lane], wg1 = w_gate[r1];
  const float bj = b_jump[0], bg = b_gate[0];

  v2f hv2[22];
#pragma unroll
  for (int k = 0; k < 22; k++) hv2[k] = (v2f){0.f, 0.f};
  float hprev = 0.0f;

  float ptr = wrap256(theta[0]);

  const float* gxr = gxp + (size_t)b * TN * GXS;
  const int o0 = jj, o1 = SDN + jj, o2 = 2 * SDN + jj;
  float* hb = hbuf + (size_t)b * TN * HS;
  float* pb = ptrbuf + (size_t)b * TN;

  // 2-deep prefetch: A = even t, B = odd t
  float pA0 = gxr[o0], pA1 = gxr[o1], pA2 = gxr[o2];
  float pB0 = gxr[GXS + o0], pB1 = gxr[GXS + o1], pB2 = gxr[GXS + o2];

  // prologue: taps at initial ptr (normalized) + pre-read of J/G window
  float wk[5]; float2 Vk[5];
  {
    int posk[5];
    taps_norm(ptr, posk, wk);
#pragma unroll
    for (int k = 0; k < 5; k++) Vk[k] = JG[posk[k]];
  }
  float pjprev = 0.f, pgprev = 0.f, S2prev = 0.f;

  auto STEP = [&](int t, float pgx0, float pgx1, float pgx2) {
    // ---- A: pointer chain ----
    float dotJ = 0.f, dotG = 0.f;
#pragma unroll
    for (int k = 0; k < 5; k++) { dotJ += wk[k] * Vk[k].x; dotG += wk[k] * Vk[k].y; }
    float Jv = fmaf(pjprev, S2prev, dotJ);
    float Gv = fmaf(pgprev, S2prev, dotG);
    float jump = 256.0f * sigm(Jv + bj);
    float gate = sigm(Gv + bg);
    float delta = wrap256(jump - ptr + 128.0f) - 128.0f;
    float ptr2 = wrap256(ptr + gate * delta);

    // taps(ptr2): unnormalized + inv
    float tbase = floorf(ptr2);
    float frac = ptr2 - tbase;
    int ib = (int)tbase;
    float e2[5], s = 0.f; int pos2[5];
#pragma unroll
    for (int k = 0; k < 5; k++) {
      float d = (float)(k - 2) - frac;
      e2[k] = __expf(-(d * d) * 0.125f);
      s += e2[k];
      pos2[k] = (ib + k - 2) & 255;
    }
    float inv2 = 1.0f / s;
    // pre-read J/G for next iteration (before this iter's ds_adds)
    float2 Vk2[5];
#pragma unroll
    for (int k = 0; k < 5; k++) Vk2[k] = JG[pos2[k]];
    float w2n[5], S2 = 0.f;
#pragma unroll
    for (int k = 0; k < 5; k++) { w2n[k] = e2[k] * inv2; S2 = fmaf(w2n[k], w2n[k], S2); }
    if (lane == 0) pb[t] = ptr2;

    // ---- B: h chain ----
    v2f ar = (v2f){bhr, 0.f}, az = (v2f){bhz, 0.f}, an = (v2f){bhn, 0.f};
#pragma unroll
    for (int k = 0; k < 21; k++) {
      v2f h2 = hv2[k];
      ar = __builtin_elementwise_fma(Whr[k], h2, ar);
      az = __builtin_elementwise_fma(Whz[k], h2, az);
      an = __builtin_elementwise_fma(Whn[k], h2, an);
    }
    float ghr = ar.x + ar.y, ghz = az.x + az.y, ghn = an.x + an.y;
    float rg = sigm(pgx0 + ghr);
    float zg = sigm(pgx1 + ghz);
    float ng = tanhfast(pgx2 + rg * ghn);
    float hn = (1.0f - zg) * ng + zg * hprev;
    hprev = hn;
    if (lane < SDN) {
      h_buf[lane] = hn;
      hb[(size_t)t * HS + lane] = hn;
    }
    __builtin_amdgcn_wave_barrier();
    asm volatile("" ::: "memory");   // forbid hoisting the broadcast reads above the stores

    // broadcast h' (uniform LDS reads)
#pragma unroll
    for (int i = 0; i < 11; i++) {
      float4 v = *(const f4ma*)(&h_buf[i * 4]);
      hv2[2 * i]     = (v2f){v.x, v.y};
      hv2[2 * i + 1] = (v2f){v.z, v.w};
    }

    // u = tanh(Wb h' + bb), dims lane, lane+64
    v2f a0 = (v2f){bb0, 0.f}, a1 = (v2f){bb1, 0.f};
#pragma unroll
    for (int k = 0; k < 21; k++) {
      v2f h2 = hv2[k];
      a0 = __builtin_elementwise_fma(Wb0[k], h2, a0);
      a1 = __builtin_elementwise_fma(Wb1[k], h2, a1);
    }
    float u0 = tanhfast(a0.x + a0.y);
    float u1 = tanhfast(a1.x + a1.y);

    float pjs = wave_sum64(u0 * wj0 + u1 * wj1);
    float pgs = wave_sum64(u0 * wg0 + u1 * wg1);

    // ---- C: J/G scatter-add (lanes 0..4) ----
    int p2sel = pos2[0]; float w2sel = w2n[0];
#pragma unroll
    for (int k = 1; k < 5; k++) {
      if (lane == k) { p2sel = pos2[k]; w2sel = w2n[k]; }
    }
    if (lane < 5) {
      atomicAdd(&JG[p2sel].x, w2sel * pjs);
      atomicAdd(&JG[p2sel].y, w2sel * pgs);
    }

    // rotate loop state
#pragma unroll
    for (int k = 0; k < 5; k++) { wk[k] = w2n[k]; Vk[k] = Vk2[k]; }
    S2prev = S2; pjprev = pjs; pgprev = pgs; ptr = ptr2;
  };

  for (int t = 0; t < TN; t += 2) {
    STEP(t, pA0, pA1, pA2);
    if (t + 2 < TN) {
      const float* g = gxr + (size_t)(t + 2) * GXS;
      pA0 = g[o0]; pA1 = g[o1]; pA2 = g[o2];
    }
    STEP(t + 1, pB0, pB1, pB2);
    if (t + 3 < TN) {
      const float* g = gxr + (size_t)(t + 3) * GXS;
      pB0 = g[o0]; pB1 = g[o1]; pB2 = g[o2];
    }
  }
}

// ---------------- r reconstruction ----------------
__global__ __launch_bounds__(64)
void rfinal_kernel(const float* __restrict__ hbuf, const float* __restrict__ ptrbuf,
                   const float* __restrict__ w_bridge, const float* __restrict__ b_bridge,
                   float* __restrict__ rbuf) {
  const int b = blockIdx.x;
  const int chunk = blockIdx.y;
  const int lane = threadIdx.x;
  const int t0 = chunk * 128;
  const int r1 = lane + 64;

  __shared__ float c_lds[128];

  const float* pb = ptrbuf + (size_t)b * TN;
  float ptrf = pb[TN - 1];
  int posf[5]; float wf[5];
  taps_norm(ptrf, posf, wf);

#pragma unroll
  for (int rr = 0; rr < 2; rr++) {
    int tt = rr * 64 + lane;
    int p2[5]; float w2[5];
    taps_norm(pb[t0 + tt], p2, w2);
    float c = 0.0f;
#pragma unroll
    for (int k = 0; k < 5; k++)
#pragma unroll
      for (int k2 = 0; k2 < 5; k2++)
        c += (posf[k] == p2[k2]) ? wf[k] * w2[k2] : 0.0f;
    c_lds[tt] = c;
  }
  __builtin_amdgcn_wave_barrier();
  asm volatile("" ::: "memory");

  const v2f* wb2 = (const v2f*)w_bridge;
  v2f Wb0[21], Wb1[21];
#pragma unroll
  for (int k = 0; k < 21; k++) { Wb0[k] = wb2[lane * 21 + k]; Wb1[k] = wb2[r1 * 21 + k]; }
  float bb0 = b_bridge[lane], bb1 = b_bridge[r1];

  float racc0 = 0.0f, racc1 = 0.0f;
  for (int tt = 0; tt < 128; tt++) {
    float ct = c_lds[tt];
    if (ct != 0.0f) {
      const f4ma* hp = (const f4ma*)(hbuf + ((size_t)b * TN + t0 + tt) * HS);
      v2f hx[22];
#pragma unroll
      for (int i = 0; i < 11; i++) {
        float4 v = hp[i];
        hx[2 * i]     = (v2f){v.x, v.y};
        hx[2 * i + 1] = (v2f){v.z, v.w};
      }
      v2f a0 = (v2f){bb0, 0.f}, a1 = (v2f){bb1, 0.f};
#pragma unroll
      for (int k = 0; k < 21; k++) {
        a0 = __builtin_elementwise_fma(Wb0[k], hx[k], a0);
        a1 = __builtin_elementwise_fma(Wb1[k], hx[k], a1);
      }
      racc0 += ct * tanhfast(a0.x + a0.y);
      racc1 += ct * tanhfast(a1.x + a1.y);
    }
  }
  atomicAdd(&rbuf[b * DD + lane], racc0);
  atomicAdd(&rbuf[b * DD + 64 + lane], racc1);
}

// ---------------- classifier: 4 batch rows per block ----------------
__global__ __launch_bounds__(256)
void cls_kernel(const float* __restrict__ rbuf, const float* __restrict__ w_cls,
                const float* __restrict__ b_cls, float* __restrict__ out) {
  const int b0 = blockIdx.x * 4;
  const int tid = threadIdx.x;
  __shared__ __align__(16) float r[4 * DD];
  for (int i = tid; i < 4 * DD; i += 256) r[i] = rbuf[(size_t)b0 * DD + i];
  __syncthreads();

  for (int c = tid; c < NCN; c += 256) {
    float bcv = b_cls[c];
    float a0 = bcv, a1 = bcv, a2 = bcv, a3 = bcv;
    const float* wrow = &w_cls[(size_t)c * DD];
#pragma unroll
    for (int d4 = 0; d4 < DD / 4; d4++) {
      float4 wv = *reinterpret_cast<const float4*>(&wrow[d4 * 4]);
      float4 r0 = *(const f4ma*)(&r[0 * DD + d4 * 4]);
      float4 r1 = *(const f4ma*)(&r[1 * DD + d4 * 4]);
      float4 r2 = *(const f4ma*)(&r[2 * DD + d4 * 4]);
      float4 r3 = *(const f4ma*)(&r[3 * DD + d4 * 4]);
      a0 += wv.x * r0.x + wv.y * r0.y + wv.z * r0.z + wv.w * r0.w;
      a1 += wv.x * r1.x + wv.y * r1.y + wv.z * r1.z + wv.w * r1.w;
      a2 += wv.x * r2.x + wv.y * r2.y + wv.z * r2.z + wv.w * r2.w;
      a3 += wv.x * r3.x + wv.y * r3.y + wv.z * r3.z + wv.w * r3.w;
    }
    out[(size_t)(b0 + 0) * NCN + c] = a0;
    out[(size_t)(b0 + 1) * NCN + c] = a1;
    out[(size_t)(b0 + 2) * NCN + c] = a2;
    out[(size_t)(b0 + 3) * NCN + c] = a3;
  }
}

extern "C" void kernel_launch(void* const* d_in, const int* in_sizes, int n_in,
                              void* d_out, int out_size, void* d_ws, size_t ws_size,
                              hipStream_t stream) {
  const float* x        = (const float*)d_in[0];
  const float* theta    = (const float*)d_in[1];
  const float* w_proj   = (const float*)d_in[2];
  const float* b_proj   = (const float*)d_in[3];
  const float* w_ih     = (const float*)d_in[4];
  const float* w_hh     = (const float*)d_in[5];
  const float* b_ih     = (const float*)d_in[6];
  const float* b_hh     = (const float*)d_in[7];
  const float* w_bridge = (const float*)d_in[8];
  const float* b_bridge = (const float*)d_in[9];
  const float* w_jump   = (const float*)d_in[10];
  const float* b_jump   = (const float*)d_in[11];
  const float* w_gate   = (const float*)d_in[12];
  const float* b_gate   = (const float*)d_in[13];
  const float* w_cls    = (const float*)d_in[14];
  const float* b_cls    = (const float*)d_in[15];
  float* out = (float*)d_out;

  char* ws = (char*)d_ws;
  size_t off = 0;
  float* gxp    = (float*)(ws + off); off += (size_t)BT * GXS * 4;
  float* hbuf   = (float*)(ws + off); off += (size_t)BN * TN * HS * 4;
  float* ptrbuf = (float*)(ws + off); off += (size_t)BN * TN * 4;
  float* rbuf   = (float*)(ws + off); off += (size_t)BN * DD * 4;
  float* Wc     = (float*)(ws + off); off += (((size_t)G3N * INN * 4 + 255) & ~(size_t)255);
  float* bc     = (float*)(ws + off); off += 512;

  hipMemsetAsync(rbuf, 0, (size_t)BN * DD * 4, stream);
  prep_kernel<<<32, 256, 0, stream>>>(w_ih, w_proj, b_proj, b_ih, Wc, bc);
  gx_gemm<<<BT / 256, 256, 0, stream>>>(x, Wc, bc, gxp);
  rec_kernel<<<BN, 64, 0, stream>>>(gxp, w_hh, b_hh, w_bridge, b_bridge,
                                    w_jump, b_jump, w_gate, b_gate, theta, hbuf, ptrbuf);
  dim3 gfin(BN, 4);
  rfinal_kernel<<<gfin, 64, 0, stream>>>(hbuf, ptrbuf, w_bridge, b_bridge, rbuf);
  cls_kernel<<<BN / 4, 256, 0, stream>>>(rbuf, w_cls, b_cls, out);
}